// Round 2
// baseline (356.228 us; speedup 1.0000x reference)
//
#include <hip/hip_runtime.h>
#include <hip/hip_bf16.h>

#define NQ 8
#define DIM 256
#define NB 16
#define NW 16
#define VOCABN 50257
#define EMBN 512

// ---------- wave64 helpers ----------
__device__ __forceinline__ float2 shfl2(float2 a, int m){
  float2 r; r.x = __shfl_xor(a.x, m, 64); r.y = __shfl_xor(a.y, m, 64); return r;
}
__device__ __forceinline__ float wave_sum(float x){
  #pragma unroll
  for (int off = 1; off < 64; off <<= 1) x += __shfl_xor(x, off, 64);
  return x;
}

// RY pair update: a0' = c a0 - s a1 ; a1' = s a0 + c a1  (real matrix)
__device__ __forceinline__ void ry_pair(float2& a0, float2& a1, float c, float s){
  float2 n0 = make_float2(c*a0.x - s*a1.x, c*a0.y - s*a1.y);
  float2 n1 = make_float2(s*a0.x + c*a1.x, s*a0.y + c*a1.y);
  a0 = n0; a1 = n1;
}
// RX pair update: a0' = c a0 - i s a1 ; a1' = -i s a0 + c a1
__device__ __forceinline__ void rx_pair(float2& a0, float2& a1, float c, float s){
  float2 n0 = make_float2(c*a0.x + s*a1.y, c*a0.y - s*a1.x);
  float2 n1 = make_float2(c*a1.x + s*a0.y, c*a1.y - s*a0.x);
  a0 = n0; a1 = n1;
}

// State layout: thread(lane) holds amplitudes idx = (r<<6)|lane, r=0..3.
// idx bit k: k<6 -> lane bit, k=6 -> r bit0, k=7 -> r bit1. Qubit q <-> bit (7-q).
__device__ __forceinline__ void apply_gate(float2 v[4], int lane, int kind, int cbit, int tbit,
                                           float c, float s){
  if (kind == 0){ // RY on bit tbit
    if (tbit == 7){ ry_pair(v[0], v[2], c, s); ry_pair(v[1], v[3], c, s); }
    else if (tbit == 6){ ry_pair(v[0], v[1], c, s); ry_pair(v[2], v[3], c, s); }
    else {
      int m = 1 << tbit;
      #pragma unroll
      for (int r = 0; r < 4; ++r){
        float2 w = shfl2(v[r], m);
        float sg = (lane & m) ? s : -s;
        v[r] = make_float2(c*v[r].x + sg*w.x, c*v[r].y + sg*w.y);
      }
    }
  } else { // CRX: control bit cbit, target bit tbit
    if (tbit >= 6){
      if (cbit >= 6){
        if (cbit == 7) rx_pair(v[2], v[3], c, s);
        else           rx_pair(v[1], v[3], c, s);
      } else {
        int cm = 1 << cbit;
        if (lane & cm){
          if (tbit == 7){ rx_pair(v[0], v[2], c, s); rx_pair(v[1], v[3], c, s); }
          else          { rx_pair(v[0], v[1], c, s); rx_pair(v[2], v[3], c, s); }
        }
      }
    } else {
      int m = 1 << tbit;
      if (cbit >= 6){
        int r0 = (cbit == 6) ? 1 : 2;
        float2 w0 = shfl2(v[r0], m);
        float2 w1 = shfl2(v[3], m);
        v[r0] = make_float2(c*v[r0].x + s*w0.y, c*v[r0].y - s*w0.x);
        v[3]  = make_float2(c*v[3].x  + s*w1.y, c*v[3].y  - s*w1.x);
      } else {
        int cm = 1 << cbit;
        bool act = (lane & cm) != 0;
        #pragma unroll
        for (int r = 0; r < 4; ++r){
          float2 w = shfl2(v[r], m);
          if (act) v[r] = make_float2(c*v[r].x + s*w.y, c*v[r].y - s*w.x);
        }
      }
    }
  }
}

// One sim14 layer = 32 gates. cs[g] = (cos(th/2), sin(th/2)).
__device__ __forceinline__ void sim32(float2 v[4], int lane, const float2* __restrict__ cs){
  constexpr int KIND[32] = {0,0,0,0,0,0,0,0, 1,1,1,1,1,1,1,1, 0,0,0,0,0,0,0,0, 1,1,1,1,1,1,1,1};
  constexpr int CB[32]   = {0,0,0,0,0,0,0,0, 0,1,2,3,4,5,6,7, 0,0,0,0,0,0,0,0, 0,7,6,5,4,3,2,1};
  constexpr int TB[32]   = {7,6,5,4,3,2,1,0, 7,0,1,2,3,4,5,6, 7,6,5,4,3,2,1,0, 1,0,7,6,5,4,3,2};
  #pragma unroll
  for (int g = 0; g < 32; ++g){
    float2 p = cs[g];
    apply_gate(v, lane, KIND[g], CB[g], TB[g], p.x, p.y);
  }
}

__device__ __forceinline__ void measure_xyz(const float2 v[4], int lane, float* exps){
  #pragma unroll
  for (int q = 0; q < 8; ++q){
    const int t = 7 - q;
    float xr = 0.f, xi = 0.f, zz = 0.f;
    if (t == 7){
      #pragma unroll
      for (int r = 0; r < 2; ++r){
        float2 a0 = v[r], a1 = v[r+2];
        xr += a0.x*a1.x + a0.y*a1.y;
        xi += a0.x*a1.y - a0.y*a1.x;
        zz += (a0.x*a0.x + a0.y*a0.y) - (a1.x*a1.x + a1.y*a1.y);
      }
    } else if (t == 6){
      #pragma unroll
      for (int r = 0; r < 4; r += 2){
        float2 a0 = v[r], a1 = v[r+1];
        xr += a0.x*a1.x + a0.y*a1.y;
        xi += a0.x*a1.y - a0.y*a1.x;
        zz += (a0.x*a0.x + a0.y*a0.y) - (a1.x*a1.x + a1.y*a1.y);
      }
    } else {
      int m = 1 << t;
      #pragma unroll
      for (int r = 0; r < 4; ++r){
        float2 a = v[r];
        float2 w = shfl2(a, m);
        if (!(lane & m)){
          xr += a.x*w.x + a.y*w.y;
          xi += a.x*w.y - a.y*w.x;
          zz += (a.x*a.x + a.y*a.y) - (w.x*w.x + w.y*w.y);
        }
      }
    }
    xr = wave_sum(xr); xi = wave_sum(xi); zz = wave_sum(zz);
    if (lane == 0){ exps[q] = 2.f*xr; exps[8+q] = 2.f*xi; exps[16+q] = zz; }
  }
}

// ---------- K1: fused prep + quantum pipeline, one block per batch element ----------
__global__ __launch_bounds__(1024) void k_sim(
    const int* __restrict__ x, const float* __restrict__ embW,
    const float* __restrict__ e2rW, const float* __restrict__ e2rb,
    const float* __restrict__ mixri, const float* __restrict__ qff,
    const float* __restrict__ poly,
    const float* __restrict__ ff1W, const float* __restrict__ ff1b,
    float* __restrict__ hT, float* __restrict__ fprobs)
{
  const int b = blockIdx.x;
  const int tid = threadIdx.x;
  const int w = tid >> 6;
  const int lane = tid & 63;

  __shared__ float2 wcs_s[NW][64];
  __shared__ float2 qcs_s[32];
  __shared__ float  ssum_s;
  __shared__ float2 stall[NW][DIM];
  __shared__ float2 partial[4][DIM];
  __shared__ float2 work[DIM];
  __shared__ float2 accs[DIM];
  __shared__ float exps[24];

  // ---- phase 0: rotation params (replaces old k_prep) ----
  {
    const int j = lane;
    const int tok = x[b*NW + w];
    const float4* er  = (const float4*)(embW + (size_t)tok * EMBN);
    const float4* wr4 = (const float4*)(e2rW + (size_t)j * EMBN);
    float acc = e2rb[j];
    #pragma unroll 4
    for (int k = 0; k < EMBN/4; ++k){
      float4 e = er[k], w4 = wr4[k];
      acc += e.x*w4.x + e.y*w4.y + e.z*w4.z + e.w*w4.w;
    }
    float th = 0.5f * acc;
    wcs_s[w][j] = make_float2(cosf(th), sinf(th));
    if (tid < 32){ float t = 0.5f * qff[tid]; qcs_s[tid] = make_float2(cosf(t), sinf(t)); }
    if (tid == 0){
      float ssum = 0.f;
      #pragma unroll
      for (int i = 0; i < 16; ++i){
        float mr = mixri[2*i], mi = mixri[2*i+1];
        ssum += sqrtf(mr*mr + mi*mi);
      }
      ssum_s = fmaxf(ssum, 1e-12f);
    }
    if (tid < DIM){
      float p0 = poly[0];
      float one = (tid == 0) ? 1.f : 0.f;
      work[tid] = make_float2(one, 0.f);
      accs[tid] = make_float2(p0*one, 0.f);
    }
  }
  __syncthreads();

  const float inv_ssum = 1.f / ssum_s;
  const float2 coef = make_float2(mixri[2*w]*inv_ssum, mixri[2*w+1]*inv_ssum);
  const float2* mycs = &wcs_s[w][0];

  for (int d = 1; d <= 3; ++d){
    float2 v[4];
    #pragma unroll
    for (int r = 0; r < 4; ++r) v[r] = work[(r<<6) | lane];
    for (int l = 0; l < 2; ++l) sim32(v, lane, mycs + 32*l);
    #pragma unroll
    for (int r = 0; r < 4; ++r){
      float2 a = v[r];
      stall[w][(r<<6) | lane] = make_float2(coef.x*a.x - coef.y*a.y, coef.x*a.y + coef.y*a.x);
    }
    __syncthreads();
    {
      int idx = tid & 255, grp = tid >> 8;
      float2 s = make_float2(0.f, 0.f);
      #pragma unroll
      for (int ww = 0; ww < 4; ++ww){
        float2 a = stall[grp*4 + ww][idx];
        s.x += a.x; s.y += a.y;
      }
      partial[grp][idx] = s;
    }
    __syncthreads();
    if (tid < DIM){
      float2 s = make_float2(0.f, 0.f);
      #pragma unroll
      for (int g2 = 0; g2 < 4; ++g2){ s.x += partial[g2][tid].x; s.y += partial[g2][tid].y; }
      float pd = poly[d];
      work[tid] = s;
      accs[tid].x += pd*s.x; accs[tid].y += pd*s.y;
    }
    __syncthreads();
  }

  const float psum = fabsf(poly[0]) + fabsf(poly[1]) + fabsf(poly[2]) + fabsf(poly[3]);
  if (tid < DIM){
    work[tid] = make_float2(accs[tid].x/psum, accs[tid].y/psum);
  }
  __syncthreads();

  if (w == 0){
    float2 v[4];
    float ss = 0.f;
    #pragma unroll
    for (int r = 0; r < 4; ++r){
      float2 m = work[(r<<6) | lane];
      v[r] = m; ss += m.x*m.x + m.y*m.y;
    }
    ss = wave_sum(ss);
    float fp = sqrtf(ss);
    if (lane == 0) fprobs[b] = fp;
    float inv = 1.f / fmaxf(fp, 1e-12f);
    #pragma unroll
    for (int r = 0; r < 4; ++r){ v[r].x *= inv; v[r].y *= inv; }
    sim32(v, lane, &qcs_s[0]); // single layer, shared params
    measure_xyz(v, lane, exps);
  }
  __syncthreads();

  if (tid < EMBN){
    float a = ff1b[tid];
    const float* wr = ff1W + tid*24;
    #pragma unroll
    for (int m2 = 0; m2 < 24; ++m2) a += exps[m2]*wr[m2];
    a = fmaxf(a, 0.f);
    hT[tid*NB + b] = a;   // k-major layout hT[k][b]
  }
}

// ---------- K2: op = h @ ff2_W.T + ff2_b ; plus mean(final_probs) ----------
// 128 vocab rows per block; 256 threads = 2 k-halves per row for 2x wave count.
// hT staged in LDS (broadcast reads are conflict-free); global pipe streams ff2W only.
__global__ __launch_bounds__(256) void k_out(
    const float* __restrict__ hT, const float* __restrict__ ff2W,
    const float* __restrict__ ff2b, const float* __restrict__ fprobs,
    float* __restrict__ out)
{
  __shared__ float4 smem[2048];   // 32 KB: hT[k][b] as float4 (b-quads), later reused for reduction
  const int tid = threadIdx.x;

  if (blockIdx.x == 0 && tid == 0){
    float s = 0.f;
    #pragma unroll
    for (int i = 0; i < 16; ++i) s += fprobs[i];
    out[(size_t)NB*VOCABN] = s * (1.f/16.f);
  }

  { // stage hT -> LDS (coalesced)
    const float4* hT4 = (const float4*)hT;
    #pragma unroll
    for (int i = 0; i < 8; ++i) smem[i*256 + tid] = hT4[i*256 + tid];
  }
  __syncthreads();

  const int rrow = tid & 127;
  const int half = tid >> 7;
  const int row  = blockIdx.x * 128 + rrow;
  const bool valid = (row < VOCABN);

  float4 a0 = make_float4(0,0,0,0), a1 = a0, a2 = a0, a3 = a0;

  if (valid){
    const float4* wv = (const float4*)(ff2W + (size_t)row * EMBN) + half*64;
    const int kbase = half*256;
    #pragma unroll 8
    for (int c = 0; c < 64; ++c){
      float4 wq = wv[c];
      const int k0 = (kbase + c*4) << 2;   // float4 index of (k, bq=0)
      float4 h00 = smem[k0+0],  h01 = smem[k0+1],  h02 = smem[k0+2],  h03 = smem[k0+3];
      float4 h10 = smem[k0+4],  h11 = smem[k0+5],  h12 = smem[k0+6],  h13 = smem[k0+7];
      float4 h20 = smem[k0+8],  h21 = smem[k0+9],  h22 = smem[k0+10], h23 = smem[k0+11];
      float4 h30 = smem[k0+12], h31 = smem[k0+13], h32 = smem[k0+14], h33 = smem[k0+15];
      a0.x += wq.x*h00.x + wq.y*h10.x + wq.z*h20.x + wq.w*h30.x;
      a0.y += wq.x*h00.y + wq.y*h10.y + wq.z*h20.y + wq.w*h30.y;
      a0.z += wq.x*h00.z + wq.y*h10.z + wq.z*h20.z + wq.w*h30.z;
      a0.w += wq.x*h00.w + wq.y*h10.w + wq.z*h20.w + wq.w*h30.w;
      a1.x += wq.x*h01.x + wq.y*h11.x + wq.z*h21.x + wq.w*h31.x;
      a1.y += wq.x*h01.y + wq.y*h11.y + wq.z*h21.y + wq.w*h31.y;
      a1.z += wq.x*h01.z + wq.y*h11.z + wq.z*h21.z + wq.w*h31.z;
      a1.w += wq.x*h01.w + wq.y*h11.w + wq.z*h21.w + wq.w*h31.w;
      a2.x += wq.x*h02.x + wq.y*h12.x + wq.z*h22.x + wq.w*h32.x;
      a2.y += wq.x*h02.y + wq.y*h12.y + wq.z*h22.y + wq.w*h32.y;
      a2.z += wq.x*h02.z + wq.y*h12.z + wq.z*h22.z + wq.w*h32.z;
      a2.w += wq.x*h02.w + wq.y*h12.w + wq.z*h22.w + wq.w*h32.w;
      a3.x += wq.x*h03.x + wq.y*h13.x + wq.z*h23.x + wq.w*h33.x;
      a3.y += wq.x*h03.y + wq.y*h13.y + wq.z*h23.y + wq.w*h33.y;
      a3.z += wq.x*h03.z + wq.y*h13.z + wq.z*h23.z + wq.w*h33.z;
      a3.w += wq.x*h03.w + wq.y*h13.w + wq.z*h23.w + wq.w*h33.w;
    }
  }
  __syncthreads();   // done reading hT region

  // cross-half reduction via LDS, transposed float4 layout (conflict-free)
  if (half == 1){
    smem[0*128 + rrow] = a0;
    smem[1*128 + rrow] = a1;
    smem[2*128 + rrow] = a2;
    smem[3*128 + rrow] = a3;
  }
  __syncthreads();
  if (half == 0 && valid){
    float4 b0 = smem[0*128 + rrow], b1 = smem[1*128 + rrow];
    float4 b2 = smem[2*128 + rrow], b3 = smem[3*128 + rrow];
    a0.x += b0.x; a0.y += b0.y; a0.z += b0.z; a0.w += b0.w;
    a1.x += b1.x; a1.y += b1.y; a1.z += b1.z; a1.w += b1.w;
    a2.x += b2.x; a2.y += b2.y; a2.z += b2.z; a2.w += b2.w;
    a3.x += b3.x; a3.y += b3.y; a3.z += b3.z; a3.w += b3.w;
    const float bias = ff2b[row];
    out[(size_t) 0*VOCABN + row] = a0.x + bias;
    out[(size_t) 1*VOCABN + row] = a0.y + bias;
    out[(size_t) 2*VOCABN + row] = a0.z + bias;
    out[(size_t) 3*VOCABN + row] = a0.w + bias;
    out[(size_t) 4*VOCABN + row] = a1.x + bias;
    out[(size_t) 5*VOCABN + row] = a1.y + bias;
    out[(size_t) 6*VOCABN + row] = a1.z + bias;
    out[(size_t) 7*VOCABN + row] = a1.w + bias;
    out[(size_t) 8*VOCABN + row] = a2.x + bias;
    out[(size_t) 9*VOCABN + row] = a2.y + bias;
    out[(size_t)10*VOCABN + row] = a2.z + bias;
    out[(size_t)11*VOCABN + row] = a2.w + bias;
    out[(size_t)12*VOCABN + row] = a3.x + bias;
    out[(size_t)13*VOCABN + row] = a3.y + bias;
    out[(size_t)14*VOCABN + row] = a3.z + bias;
    out[(size_t)15*VOCABN + row] = a3.w + bias;
  }
}

extern "C" void kernel_launch(void* const* d_in, const int* in_sizes, int n_in,
                              void* d_out, int out_size, void* d_ws, size_t ws_size,
                              hipStream_t stream)
{
  const int*   x     = (const int*)  d_in[0];
  const float* embW  = (const float*)d_in[1];
  const float* e2rW  = (const float*)d_in[2];
  const float* e2rb  = (const float*)d_in[3];
  const float* poly  = (const float*)d_in[4];
  const float* mixri = (const float*)d_in[5];
  const float* qff   = (const float*)d_in[6];
  const float* ff1W  = (const float*)d_in[7];
  const float* ff1b  = (const float*)d_in[8];
  const float* ff2W  = (const float*)d_in[9];
  const float* ff2b  = (const float*)d_in[10];
  float* out = (float*)d_out;
  float* ws  = (float*)d_ws;

  float* hT     = ws;          // 512*16 = 8192 floats
  float* fprobs = ws + 8192;   // 16 floats

  k_sim<<<NB, 1024, 0, stream>>>(x, embW, e2rW, e2rb, mixri, qff, poly, ff1W, ff1b, hT, fprobs);
  k_out<<<(VOCABN + 127)/128, 256, 0, stream>>>(hT, ff2W, ff2b, fprobs, out);
}

// Round 3
// 301.208 us; speedup vs baseline: 1.1827x; 1.1827x over previous
//
#include <hip/hip_runtime.h>
#include <hip/hip_bf16.h>

#define NQ 8
#define DIM 256
#define NB 16
#define NW 16
#define VOCABN 50257
#define EMBN 512

// ---------- wave64 helpers ----------
__device__ __forceinline__ float2 shfl2(float2 a, int m){
  float2 r; r.x = __shfl_xor(a.x, m, 64); r.y = __shfl_xor(a.y, m, 64); return r;
}
__device__ __forceinline__ float wave_sum(float x){
  #pragma unroll
  for (int off = 1; off < 64; off <<= 1) x += __shfl_xor(x, off, 64);
  return x;
}

// RY pair update: a0' = c a0 - s a1 ; a1' = s a0 + c a1  (real matrix)
__device__ __forceinline__ void ry_pair(float2& a0, float2& a1, float c, float s){
  float2 n0 = make_float2(c*a0.x - s*a1.x, c*a0.y - s*a1.y);
  float2 n1 = make_float2(s*a0.x + c*a1.x, s*a0.y + c*a1.y);
  a0 = n0; a1 = n1;
}
// RX pair update: a0' = c a0 - i s a1 ; a1' = -i s a0 + c a1
__device__ __forceinline__ void rx_pair(float2& a0, float2& a1, float c, float s){
  float2 n0 = make_float2(c*a0.x + s*a1.y, c*a0.y - s*a1.x);
  float2 n1 = make_float2(c*a1.x + s*a0.y, c*a1.y - s*a0.x);
  a0 = n0; a1 = n1;
}

// State layout: thread(lane) holds amplitudes idx = (r<<6)|lane, r=0..3.
// idx bit k: k<6 -> lane bit, k=6 -> r bit0, k=7 -> r bit1. Qubit q <-> bit (7-q).
__device__ __forceinline__ void apply_gate(float2 v[4], int lane, int kind, int cbit, int tbit,
                                           float c, float s){
  if (kind == 0){ // RY on bit tbit
    if (tbit == 7){ ry_pair(v[0], v[2], c, s); ry_pair(v[1], v[3], c, s); }
    else if (tbit == 6){ ry_pair(v[0], v[1], c, s); ry_pair(v[2], v[3], c, s); }
    else {
      int m = 1 << tbit;
      #pragma unroll
      for (int r = 0; r < 4; ++r){
        float2 w = shfl2(v[r], m);
        float sg = (lane & m) ? s : -s;
        v[r] = make_float2(c*v[r].x + sg*w.x, c*v[r].y + sg*w.y);
      }
    }
  } else { // CRX: control bit cbit, target bit tbit
    if (tbit >= 6){
      if (cbit >= 6){
        if (cbit == 7) rx_pair(v[2], v[3], c, s);
        else           rx_pair(v[1], v[3], c, s);
      } else {
        int cm = 1 << cbit;
        if (lane & cm){
          if (tbit == 7){ rx_pair(v[0], v[2], c, s); rx_pair(v[1], v[3], c, s); }
          else          { rx_pair(v[0], v[1], c, s); rx_pair(v[2], v[3], c, s); }
        }
      }
    } else {
      int m = 1 << tbit;
      if (cbit >= 6){
        int r0 = (cbit == 6) ? 1 : 2;
        float2 w0 = shfl2(v[r0], m);
        float2 w1 = shfl2(v[3], m);
        v[r0] = make_float2(c*v[r0].x + s*w0.y, c*v[r0].y - s*w0.x);
        v[3]  = make_float2(c*v[3].x  + s*w1.y, c*v[3].y  - s*w1.x);
      } else {
        int cm = 1 << cbit;
        bool act = (lane & cm) != 0;
        #pragma unroll
        for (int r = 0; r < 4; ++r){
          float2 w = shfl2(v[r], m);
          if (act) v[r] = make_float2(c*v[r].x + s*w.y, c*v[r].y - s*w.x);
        }
      }
    }
  }
}

// One sim14 layer = 32 gates. cs[g] = (cos(th/2), sin(th/2)).
__device__ __forceinline__ void sim32(float2 v[4], int lane, const float2* __restrict__ cs){
  constexpr int KIND[32] = {0,0,0,0,0,0,0,0, 1,1,1,1,1,1,1,1, 0,0,0,0,0,0,0,0, 1,1,1,1,1,1,1,1};
  constexpr int CB[32]   = {0,0,0,0,0,0,0,0, 0,1,2,3,4,5,6,7, 0,0,0,0,0,0,0,0, 0,7,6,5,4,3,2,1};
  constexpr int TB[32]   = {7,6,5,4,3,2,1,0, 7,0,1,2,3,4,5,6, 7,6,5,4,3,2,1,0, 1,0,7,6,5,4,3,2};
  #pragma unroll
  for (int g = 0; g < 32; ++g){
    float2 p = cs[g];
    apply_gate(v, lane, KIND[g], CB[g], TB[g], p.x, p.y);
  }
}

// measurement of one qubit with bit t: returns wave-reduced xr, xi, zz in lane values
__device__ __forceinline__ void measure_one(const float2 v[4], int lane, int t,
                                            float& xr, float& xi, float& zz){
  xr = 0.f; xi = 0.f; zz = 0.f;
  if (t == 7){
    #pragma unroll
    for (int r = 0; r < 2; ++r){
      float2 a0 = v[r], a1 = v[r+2];
      xr += a0.x*a1.x + a0.y*a1.y;
      xi += a0.x*a1.y - a0.y*a1.x;
      zz += (a0.x*a0.x + a0.y*a0.y) - (a1.x*a1.x + a1.y*a1.y);
    }
  } else if (t == 6){
    #pragma unroll
    for (int r = 0; r < 4; r += 2){
      float2 a0 = v[r], a1 = v[r+1];
      xr += a0.x*a1.x + a0.y*a1.y;
      xi += a0.x*a1.y - a0.y*a1.x;
      zz += (a0.x*a0.x + a0.y*a0.y) - (a1.x*a1.x + a1.y*a1.y);
    }
  } else {
    int m = 1 << t;
    #pragma unroll
    for (int r = 0; r < 4; ++r){
      float2 a = v[r];
      float2 w = shfl2(a, m);
      if (!(lane & m)){
        xr += a.x*w.x + a.y*w.y;
        xi += a.x*w.y - a.y*w.x;
        zz += (a.x*a.x + a.y*a.y) - (w.x*w.x + w.y*w.y);
      }
    }
  }
  xr = wave_sum(xr); xi = wave_sum(xi); zz = wave_sum(zz);
}

// ---------- K1: embeddings -> rotation angles -> (cos,sin); coeffs; qff (cos,sin) ----------
// 256 blocks (one per (b,w) token) x 64 threads: spreads the 64-line-scatter e2rW
// reads across 256 CUs where they cost ~3 us total (16-block fusion cost 70+ us).
__global__ __launch_bounds__(64) void k_prep(
    const int* __restrict__ x, const float* __restrict__ embW,
    const float* __restrict__ e2rW, const float* __restrict__ e2rb,
    const float* __restrict__ mixri, const float* __restrict__ qff,
    float* __restrict__ wcs, float* __restrict__ coeffs, float* __restrict__ qcs)
{
  const int p = blockIdx.x;    // 0..255 = b*16+w
  const int j = threadIdx.x;   // 0..63 rotation index
  const int tok = x[p];
  const float4* er = (const float4*)(embW + (size_t)tok * EMBN);
  const float4* wr = (const float4*)(e2rW + (size_t)j * EMBN);
  float acc = e2rb[j];
  #pragma unroll 4
  for (int k = 0; k < EMBN/4; ++k){
    float4 e = er[k], w4 = wr[k];
    acc += e.x*w4.x + e.y*w4.y + e.z*w4.z + e.w*w4.w;
  }
  float th = 0.5f * acc;
  wcs[(p*64 + j)*2 + 0] = cosf(th);
  wcs[(p*64 + j)*2 + 1] = sinf(th);
  if (p == 0){
    if (j < 32){ float t = 0.5f * qff[j]; qcs[2*j] = cosf(t); qcs[2*j+1] = sinf(t); }
    if (j < 16){
      float ssum = 0.f;
      for (int i = 0; i < 16; ++i){
        float mr = mixri[2*i], mi = mixri[2*i+1];
        ssum += sqrtf(mr*mr + mi*mi);
      }
      ssum = fmaxf(ssum, 1e-12f);
      coeffs[2*j]   = mixri[2*j]   / ssum;
      coeffs[2*j+1] = mixri[2*j+1] / ssum;
    }
  }
}

// ---------- K2: quantum pipeline, one block per batch element ----------
__global__ __launch_bounds__(1024) void k_sim(
    const float* __restrict__ wcs, const float* __restrict__ coeffs,
    const float* __restrict__ qcs, const float* __restrict__ poly,
    const float* __restrict__ ff1W, const float* __restrict__ ff1b,
    float* __restrict__ hT, float* __restrict__ fprobs)
{
  const int b = blockIdx.x;
  const int tid = threadIdx.x;
  const int w = tid >> 6;
  const int lane = tid & 63;

  __shared__ float2 wcs_s[NW*64];     // 8 KB
  __shared__ float2 qcs_s[32];
  __shared__ float2 stall[NW][DIM];   // 32 KB
  __shared__ float2 partial[4][DIM];  // 8 KB
  __shared__ float2 work[DIM];        // 2 KB
  __shared__ float2 accs[DIM];        // 2 KB
  __shared__ float  exps[24];
  __shared__ float  inv_s;
  __shared__ float  ff1_lds[EMBN*24]; // 48 KB

  // ---- stage block-wide constants (coalesced) ----
  wcs_s[tid] = ((const float2*)wcs)[b*(NW*64) + tid];
  if (tid < 32) qcs_s[tid] = ((const float2*)qcs)[tid];
  { // ff1W: 12288 floats = 3072 float4, coalesced; replaces per-thread 64-line scatter
    const float4* f4 = (const float4*)ff1W;
    float4* d4 = (float4*)ff1_lds;
    #pragma unroll
    for (int i = 0; i < 3; ++i) d4[i*1024 + tid] = f4[i*1024 + tid];
  }
  if (tid < DIM){
    float p0 = poly[0];
    float one = (tid == 0) ? 1.f : 0.f;
    work[tid] = make_float2(one, 0.f);
    accs[tid] = make_float2(p0*one, 0.f);
  }
  __syncthreads();

  const float2 coef = make_float2(coeffs[2*w], coeffs[2*w+1]);
  const float2* mycs = &wcs_s[w*64];

  for (int d = 1; d <= 3; ++d){
    float2 v[4];
    #pragma unroll
    for (int r = 0; r < 4; ++r) v[r] = work[(r<<6) | lane];
    for (int l = 0; l < 2; ++l) sim32(v, lane, mycs + 32*l);
    #pragma unroll
    for (int r = 0; r < 4; ++r){
      float2 a = v[r];
      stall[w][(r<<6) | lane] = make_float2(coef.x*a.x - coef.y*a.y, coef.x*a.y + coef.y*a.x);
    }
    __syncthreads();
    {
      int idx = tid & 255, grp = tid >> 8;
      float2 s = make_float2(0.f, 0.f);
      #pragma unroll
      for (int ww = 0; ww < 4; ++ww){
        float2 a = stall[grp*4 + ww][idx];
        s.x += a.x; s.y += a.y;
      }
      partial[grp][idx] = s;
    }
    __syncthreads();
    if (tid < DIM){
      float2 s = make_float2(0.f, 0.f);
      #pragma unroll
      for (int g2 = 0; g2 < 4; ++g2){ s.x += partial[g2][tid].x; s.y += partial[g2][tid].y; }
      float pd = poly[d];
      work[tid] = s;
      accs[tid].x += pd*s.x; accs[tid].y += pd*s.y;
    }
    __syncthreads();
  }

  const float psum = fabsf(poly[0]) + fabsf(poly[1]) + fabsf(poly[2]) + fabsf(poly[3]);
  if (tid < DIM){
    work[tid] = make_float2(accs[tid].x/psum, accs[tid].y/psum);
  }
  __syncthreads();

  // norm (wave 0) -> broadcast inverse
  if (w == 0){
    float ss = 0.f;
    #pragma unroll
    for (int r = 0; r < 4; ++r){
      float2 m = work[(r<<6) | lane];
      ss += m.x*m.x + m.y*m.y;
    }
    ss = wave_sum(ss);
    float fp = sqrtf(ss);
    if (lane == 0){
      fprobs[b] = fp;
      inv_s = 1.f / fmaxf(fp, 1e-12f);
    }
  }
  __syncthreads();

  // final circuit + measurement: waves 0..7 redundantly run the 32-gate qff circuit,
  // wave q measures only qubit q (parallelizes the 24 serial wave-reductions 8x).
  if (w < 8){
    float inv = inv_s;
    float2 v[4];
    #pragma unroll
    for (int r = 0; r < 4; ++r){
      float2 m = work[(r<<6) | lane];
      v[r] = make_float2(m.x*inv, m.y*inv);
    }
    sim32(v, lane, &qcs_s[0]);
    float xr, xi, zz;
    measure_one(v, lane, 7 - w, xr, xi, zz);
    if (lane == 0){ exps[w] = 2.f*xr; exps[8+w] = 2.f*xi; exps[16+w] = zz; }
  }
  __syncthreads();

  if (tid < EMBN){
    float a = ff1b[tid];
    const float* wr = ff1_lds + tid*24;
    #pragma unroll
    for (int m2 = 0; m2 < 24; ++m2) a += exps[m2]*wr[m2];
    a = fmaxf(a, 0.f);
    hT[tid*NB + b] = a;   // k-major layout hT[k][b]
  }
}

// ---------- K3: op = h @ ff2_W.T + ff2_b ; plus mean(final_probs) ----------
// 128 vocab rows per block; 256 threads = 2 k-halves per row for 2x wave count.
// hT staged in LDS (broadcast reads are conflict-free); global pipe streams ff2W only.
__global__ __launch_bounds__(256) void k_out(
    const float* __restrict__ hT, const float* __restrict__ ff2W,
    const float* __restrict__ ff2b, const float* __restrict__ fprobs,
    float* __restrict__ out)
{
  __shared__ float4 smem[2048];   // 32 KB
  const int tid = threadIdx.x;

  if (blockIdx.x == 0 && tid == 0){
    float s = 0.f;
    #pragma unroll
    for (int i = 0; i < 16; ++i) s += fprobs[i];
    out[(size_t)NB*VOCABN] = s * (1.f/16.f);
  }

  { // stage hT -> LDS (coalesced)
    const float4* hT4 = (const float4*)hT;
    #pragma unroll
    for (int i = 0; i < 8; ++i) smem[i*256 + tid] = hT4[i*256 + tid];
  }
  __syncthreads();

  const int rrow = tid & 127;
  const int half = tid >> 7;
  const int row  = blockIdx.x * 128 + rrow;
  const bool valid = (row < VOCABN);

  float4 a0 = make_float4(0,0,0,0), a1 = a0, a2 = a0, a3 = a0;

  if (valid){
    const float4* wv = (const float4*)(ff2W + (size_t)row * EMBN) + half*64;
    const int kbase = half*256;
    #pragma unroll 8
    for (int c = 0; c < 64; ++c){
      float4 wq = wv[c];
      const int k0 = (kbase + c*4) << 2;
      float4 h00 = smem[k0+0],  h01 = smem[k0+1],  h02 = smem[k0+2],  h03 = smem[k0+3];
      float4 h10 = smem[k0+4],  h11 = smem[k0+5],  h12 = smem[k0+6],  h13 = smem[k0+7];
      float4 h20 = smem[k0+8],  h21 = smem[k0+9],  h22 = smem[k0+10], h23 = smem[k0+11];
      float4 h30 = smem[k0+12], h31 = smem[k0+13], h32 = smem[k0+14], h33 = smem[k0+15];
      a0.x += wq.x*h00.x + wq.y*h10.x + wq.z*h20.x + wq.w*h30.x;
      a0.y += wq.x*h00.y + wq.y*h10.y + wq.z*h20.y + wq.w*h30.y;
      a0.z += wq.x*h00.z + wq.y*h10.z + wq.z*h20.z + wq.w*h30.z;
      a0.w += wq.x*h00.w + wq.y*h10.w + wq.z*h20.w + wq.w*h30.w;
      a1.x += wq.x*h01.x + wq.y*h11.x + wq.z*h21.x + wq.w*h31.x;
      a1.y += wq.x*h01.y + wq.y*h11.y + wq.z*h21.y + wq.w*h31.y;
      a1.z += wq.x*h01.z + wq.y*h11.z + wq.z*h21.z + wq.w*h31.z;
      a1.w += wq.x*h01.w + wq.y*h11.w + wq.z*h21.w + wq.w*h31.w;
      a2.x += wq.x*h02.x + wq.y*h12.x + wq.z*h22.x + wq.w*h32.x;
      a2.y += wq.x*h02.y + wq.y*h12.y + wq.z*h22.y + wq.w*h32.y;
      a2.z += wq.x*h02.z + wq.y*h12.z + wq.z*h22.z + wq.w*h32.z;
      a2.w += wq.x*h02.w + wq.y*h12.w + wq.z*h22.w + wq.w*h32.w;
      a3.x += wq.x*h03.x + wq.y*h13.x + wq.z*h23.x + wq.w*h33.x;
      a3.y += wq.x*h03.y + wq.y*h13.y + wq.z*h23.y + wq.w*h33.y;
      a3.z += wq.x*h03.z + wq.y*h13.z + wq.z*h23.z + wq.w*h33.z;
      a3.w += wq.x*h03.w + wq.y*h13.w + wq.z*h23.w + wq.w*h33.w;
    }
  }
  __syncthreads();

  if (half == 1){
    smem[0*128 + rrow] = a0;
    smem[1*128 + rrow] = a1;
    smem[2*128 + rrow] = a2;
    smem[3*128 + rrow] = a3;
  }
  __syncthreads();
  if (half == 0 && valid){
    float4 b0 = smem[0*128 + rrow], b1 = smem[1*128 + rrow];
    float4 b2 = smem[2*128 + rrow], b3 = smem[3*128 + rrow];
    a0.x += b0.x; a0.y += b0.y; a0.z += b0.z; a0.w += b0.w;
    a1.x += b1.x; a1.y += b1.y; a1.z += b1.z; a1.w += b1.w;
    a2.x += b2.x; a2.y += b2.y; a2.z += b2.z; a2.w += b2.w;
    a3.x += b3.x; a3.y += b3.y; a3.z += b3.z; a3.w += b3.w;
    const float bias = ff2b[row];
    out[(size_t) 0*VOCABN + row] = a0.x + bias;
    out[(size_t) 1*VOCABN + row] = a0.y + bias;
    out[(size_t) 2*VOCABN + row] = a0.z + bias;
    out[(size_t) 3*VOCABN + row] = a0.w + bias;
    out[(size_t) 4*VOCABN + row] = a1.x + bias;
    out[(size_t) 5*VOCABN + row] = a1.y + bias;
    out[(size_t) 6*VOCABN + row] = a1.z + bias;
    out[(size_t) 7*VOCABN + row] = a1.w + bias;
    out[(size_t) 8*VOCABN + row] = a2.x + bias;
    out[(size_t) 9*VOCABN + row] = a2.y + bias;
    out[(size_t)10*VOCABN + row] = a2.z + bias;
    out[(size_t)11*VOCABN + row] = a2.w + bias;
    out[(size_t)12*VOCABN + row] = a3.x + bias;
    out[(size_t)13*VOCABN + row] = a3.y + bias;
    out[(size_t)14*VOCABN + row] = a3.z + bias;
    out[(size_t)15*VOCABN + row] = a3.w + bias;
  }
}

extern "C" void kernel_launch(void* const* d_in, const int* in_sizes, int n_in,
                              void* d_out, int out_size, void* d_ws, size_t ws_size,
                              hipStream_t stream)
{
  const int*   x     = (const int*)  d_in[0];
  const float* embW  = (const float*)d_in[1];
  const float* e2rW  = (const float*)d_in[2];
  const float* e2rb  = (const float*)d_in[3];
  const float* poly  = (const float*)d_in[4];
  const float* mixri = (const float*)d_in[5];
  const float* qff   = (const float*)d_in[6];
  const float* ff1W  = (const float*)d_in[7];
  const float* ff1b  = (const float*)d_in[8];
  const float* ff2W  = (const float*)d_in[9];
  const float* ff2b  = (const float*)d_in[10];
  float* out = (float*)d_out;
  float* ws  = (float*)d_ws;

  float* wcs    = ws;            // 256*64*2 = 32768 floats
  float* coeffs = ws + 32768;    // 32 floats
  float* qcs    = ws + 32800;    // 64 floats
  float* hT     = ws + 32864;    // 512*16 = 8192 floats
  float* fprobs = ws + 41056;    // 16 floats

  k_prep<<<256, 64, 0, stream>>>(x, embW, e2rW, e2rb, mixri, qff, wcs, coeffs, qcs);
  k_sim <<<NB, 1024, 0, stream>>>(wcs, coeffs, qcs, poly, ff1W, ff1b, hT, fprobs);
  k_out <<<(VOCABN + 127)/128, 256, 0, stream>>>(hT, ff2W, ff2b, fprobs, out);
}

// Round 4
// 289.171 us; speedup vs baseline: 1.2319x; 1.0416x over previous
//
#include <hip/hip_runtime.h>
#include <hip/hip_bf16.h>

#define NQ 8
#define DIM 256
#define NB 16
#define NW 16
#define VOCABN 50257
#define EMBN 512

// ---------- wave64 helpers ----------
__device__ __forceinline__ float2 shfl2(float2 a, int m){
  float2 r; r.x = __shfl_xor(a.x, m, 64); r.y = __shfl_xor(a.y, m, 64); return r;
}
__device__ __forceinline__ float wave_sum(float x){
  #pragma unroll
  for (int off = 1; off < 64; off <<= 1) x += __shfl_xor(x, off, 64);
  return x;
}

// RY pair update: a0' = c a0 - s a1 ; a1' = s a0 + c a1
__device__ __forceinline__ void ry_pair(float2& a0, float2& a1, float c, float s){
  float2 n0 = make_float2(c*a0.x - s*a1.x, c*a0.y - s*a1.y);
  float2 n1 = make_float2(s*a0.x + c*a1.x, s*a0.y + c*a1.y);
  a0 = n0; a1 = n1;
}
// RX pair update: a0' = c a0 - i s a1 ; a1' = -i s a0 + c a1
__device__ __forceinline__ void rx_pair(float2& a0, float2& a1, float c, float s){
  float2 n0 = make_float2(c*a0.x + s*a1.y, c*a0.y - s*a1.x);
  float2 n1 = make_float2(c*a1.x + s*a0.y, c*a1.y - s*a0.x);
  a0 = n0; a1 = n1;
}

// State layout: lane holds amplitudes idx = (r<<6)|lane, r=0..3.
// idx bit k: k<6 -> lane bit, k=6 -> r bit0, k=7 -> r bit1. Qubit q <-> bit (7-q).
__device__ __forceinline__ void apply_gate(float2 v[4], int lane, int kind, int cbit, int tbit,
                                           float c, float s){
  if (kind == 0){ // RY
    if (tbit == 7){ ry_pair(v[0], v[2], c, s); ry_pair(v[1], v[3], c, s); }
    else if (tbit == 6){ ry_pair(v[0], v[1], c, s); ry_pair(v[2], v[3], c, s); }
    else {
      int m = 1 << tbit;
      #pragma unroll
      for (int r = 0; r < 4; ++r){
        float2 w = shfl2(v[r], m);
        float sg = (lane & m) ? s : -s;
        v[r] = make_float2(c*v[r].x + sg*w.x, c*v[r].y + sg*w.y);
      }
    }
  } else { // CRX
    if (tbit >= 6){
      if (cbit >= 6){
        if (cbit == 7) rx_pair(v[2], v[3], c, s);
        else           rx_pair(v[1], v[3], c, s);
      } else {
        int cm = 1 << cbit;
        if (lane & cm){
          if (tbit == 7){ rx_pair(v[0], v[2], c, s); rx_pair(v[1], v[3], c, s); }
          else          { rx_pair(v[0], v[1], c, s); rx_pair(v[2], v[3], c, s); }
        }
      }
    } else {
      int m = 1 << tbit;
      if (cbit >= 6){
        int r0 = (cbit == 6) ? 1 : 2;
        float2 w0 = shfl2(v[r0], m);
        float2 w1 = shfl2(v[3], m);
        v[r0] = make_float2(c*v[r0].x + s*w0.y, c*v[r0].y - s*w0.x);
        v[3]  = make_float2(c*v[3].x  + s*w1.y, c*v[3].y  - s*w1.x);
      } else {
        int cm = 1 << cbit;
        bool act = (lane & cm) != 0;
        #pragma unroll
        for (int r = 0; r < 4; ++r){
          float2 w = shfl2(v[r], m);
          if (act) v[r] = make_float2(c*v[r].x + s*w.y, c*v[r].y - s*w.x);
        }
      }
    }
  }
}

// One sim14 layer = 32 gates. cs[g] = (cos(th/2), sin(th/2)).
__device__ __forceinline__ void sim32(float2 v[4], int lane, const float2* __restrict__ cs){
  constexpr int KIND[32] = {0,0,0,0,0,0,0,0, 1,1,1,1,1,1,1,1, 0,0,0,0,0,0,0,0, 1,1,1,1,1,1,1,1};
  constexpr int CB[32]   = {0,0,0,0,0,0,0,0, 0,1,2,3,4,5,6,7, 0,0,0,0,0,0,0,0, 0,7,6,5,4,3,2,1};
  constexpr int TB[32]   = {7,6,5,4,3,2,1,0, 7,0,1,2,3,4,5,6, 7,6,5,4,3,2,1,0, 1,0,7,6,5,4,3,2};
  #pragma unroll
  for (int g = 0; g < 32; ++g){
    float2 p = cs[g];
    apply_gate(v, lane, KIND[g], CB[g], TB[g], p.x, p.y);
  }
}

// measurement of one qubit with bit t: wave-reduced xr, xi, zz
__device__ __forceinline__ void measure_one(const float2 v[4], int lane, int t,
                                            float& xr, float& xi, float& zz){
  xr = 0.f; xi = 0.f; zz = 0.f;
  if (t == 7){
    #pragma unroll
    for (int r = 0; r < 2; ++r){
      float2 a0 = v[r], a1 = v[r+2];
      xr += a0.x*a1.x + a0.y*a1.y;
      xi += a0.x*a1.y - a0.y*a1.x;
      zz += (a0.x*a0.x + a0.y*a0.y) - (a1.x*a1.x + a1.y*a1.y);
    }
  } else if (t == 6){
    #pragma unroll
    for (int r = 0; r < 4; r += 2){
      float2 a0 = v[r], a1 = v[r+1];
      xr += a0.x*a1.x + a0.y*a1.y;
      xi += a0.x*a1.y - a0.y*a1.x;
      zz += (a0.x*a0.x + a0.y*a0.y) - (a1.x*a1.x + a1.y*a1.y);
    }
  } else {
    int m = 1 << t;
    #pragma unroll
    for (int r = 0; r < 4; ++r){
      float2 a = v[r];
      float2 w = shfl2(a, m);
      if (!(lane & m)){
        xr += a.x*w.x + a.y*w.y;
        xi += a.x*w.y - a.y*w.x;
        zz += (a.x*a.x + a.y*a.y) - (w.x*w.x + w.y*w.y);
      }
    }
  }
  xr = wave_sum(xr); xi = wave_sum(xi); zz = wave_sum(zz);
}

// ---------- K1: angles -> (cos,sin); coeffs; qff (cos,sin) ----------
__global__ __launch_bounds__(64) void k_prep(
    const int* __restrict__ x, const float* __restrict__ embW,
    const float* __restrict__ e2rW, const float* __restrict__ e2rb,
    const float* __restrict__ mixri, const float* __restrict__ qff,
    float* __restrict__ wcs, float* __restrict__ coeffs, float* __restrict__ qcs)
{
  const int p = blockIdx.x;    // 0..255 = b*16+w
  const int j = threadIdx.x;   // rotation index 0..63
  const int tok = x[p];
  const float4* er = (const float4*)(embW + (size_t)tok * EMBN);
  const float4* wr = (const float4*)(e2rW + (size_t)j * EMBN);
  float acc = e2rb[j];
  #pragma unroll 4
  for (int k = 0; k < EMBN/4; ++k){
    float4 e = er[k], w4 = wr[k];
    acc += e.x*w4.x + e.y*w4.y + e.z*w4.z + e.w*w4.w;
  }
  float th = 0.5f * acc;
  wcs[(p*64 + j)*2 + 0] = cosf(th);
  wcs[(p*64 + j)*2 + 1] = sinf(th);
  if (p == 0){
    if (j < 32){ float t = 0.5f * qff[j]; qcs[2*j] = cosf(t); qcs[2*j+1] = sinf(t); }
    if (j < 16){
      float ssum = 0.f;
      for (int i = 0; i < 16; ++i){
        float mr = mixri[2*i], mi = mixri[2*i+1];
        ssum += sqrtf(mr*mr + mi*mi);
      }
      ssum = fmaxf(ssum, 1e-12f);
      coeffs[2*j]   = mixri[2*j]   / ssum;
      coeffs[2*j+1] = mixri[2*j+1] / ssum;
    }
  }
}

// ---------- degree 1: basis state -> circuit -> scaled staging ----------
__global__ __launch_bounds__(64) void k_deg1(
    const float* __restrict__ wcs, const float* __restrict__ coeffs,
    float2* __restrict__ S1)
{
  const int p = blockIdx.x, lane = threadIdx.x;
  const float2* mycs = ((const float2*)wcs) + p*64;
  float2 v[4];
  v[0] = make_float2(lane == 0 ? 1.f : 0.f, 0.f);
  v[1] = v[2] = v[3] = make_float2(0.f, 0.f);
  sim32(v, lane, mycs);
  sim32(v, lane, mycs + 32);
  const float2 coef = ((const float2*)coeffs)[p & 15];
  #pragma unroll
  for (int r = 0; r < 4; ++r){
    float2 a = v[r];
    S1[p*DIM + ((r<<6) | lane)] = make_float2(coef.x*a.x - coef.y*a.y, coef.x*a.y + coef.y*a.x);
  }
}

// ---------- degree d (d=2,3): reduce previous staging -> circuit -> staging ----------
// Each of 256 blocks redundantly reduces its b's 16 staged states (32 KB, L2-hot).
// Blocks with w==0 also update the polynomial accumulator for the PREVIOUS degree.
__global__ __launch_bounds__(64) void k_deg(
    const float2* __restrict__ Sin, float2* __restrict__ Sout,
    const float* __restrict__ wcs, const float* __restrict__ coeffs,
    const float* __restrict__ poly, float2* __restrict__ accs, int dprev)
{
  const int p = blockIdx.x, lane = threadIdx.x;
  const int b = p >> 4, w = p & 15;
  float2 v[4];
  v[0] = v[1] = v[2] = v[3] = make_float2(0.f, 0.f);
  const float2* base = Sin + b*NW*DIM;
  #pragma unroll
  for (int ww = 0; ww < NW; ++ww){
    #pragma unroll
    for (int r = 0; r < 4; ++r){
      float2 a = base[ww*DIM + ((r<<6) | lane)];
      v[r].x += a.x; v[r].y += a.y;
    }
  }
  if (w == 0){
    const float pd = poly[dprev];
    #pragma unroll
    for (int r = 0; r < 4; ++r){
      const int idx = (r<<6) | lane;
      float2 cur = make_float2(pd*v[r].x, pd*v[r].y);
      if (dprev == 1){
        if (idx == 0) cur.x += poly[0];
        accs[b*DIM + idx] = cur;
      } else {
        float2 old = accs[b*DIM + idx];
        accs[b*DIM + idx] = make_float2(old.x + cur.x, old.y + cur.y);
      }
    }
  }
  const float2* mycs = ((const float2*)wcs) + p*64;
  sim32(v, lane, mycs);
  sim32(v, lane, mycs + 32);
  const float2 coef = ((const float2*)coeffs)[w];
  #pragma unroll
  for (int r = 0; r < 4; ++r){
    float2 a = v[r];
    Sout[p*DIM + ((r<<6) | lane)] = make_float2(coef.x*a.x - coef.y*a.y, coef.x*a.y + coef.y*a.x);
  }
}

// ---------- final: mix, norm, qff circuit, measure, ff1 ----------
__global__ __launch_bounds__(512) void k_final(
    const float2* __restrict__ Sin, const float2* __restrict__ accs,
    const float* __restrict__ poly, const float* __restrict__ qcs,
    const float* __restrict__ ff1W, const float* __restrict__ ff1b,
    float* __restrict__ hT, float* __restrict__ fprobs)
{
  const int b = blockIdx.x, tid = threadIdx.x;
  const int w = tid >> 6, lane = tid & 63;
  __shared__ float2 work[DIM];
  __shared__ float  red[8];
  __shared__ float  exps[24];
  __shared__ float  inv_s;
  __shared__ float  ff1_lds[EMBN*24];   // 48 KB

  { // stage ff1W coalesced: 3072 float4 over 512 threads
    const float4* f4 = (const float4*)ff1W;
    float4* d4 = (float4*)ff1_lds;
    #pragma unroll
    for (int i = 0; i < 6; ++i) d4[i*512 + tid] = f4[i*512 + tid];
  }
  const float psum = fabsf(poly[0]) + fabsf(poly[1]) + fabsf(poly[2]) + fabsf(poly[3]);
  float ssl = 0.f;
  if (tid < DIM){
    float2 s = make_float2(0.f, 0.f);
    const float2* base = Sin + b*NW*DIM;
    #pragma unroll
    for (int ww = 0; ww < NW; ++ww){ float2 a = base[ww*DIM + tid]; s.x += a.x; s.y += a.y; }
    float2 ac = accs[b*DIM + tid];
    const float p3 = poly[3];
    s = make_float2((ac.x + p3*s.x)/psum, (ac.y + p3*s.y)/psum);
    work[tid] = s;
    ssl = s.x*s.x + s.y*s.y;
  }
  ssl = wave_sum(ssl);
  if (lane == 0) red[w] = ssl;
  __syncthreads();
  if (tid == 0){
    float fp = sqrtf(red[0] + red[1] + red[2] + red[3]);
    fprobs[b] = fp;
    inv_s = 1.f / fmaxf(fp, 1e-12f);
  }
  __syncthreads();
  { // waves 0..7 redundantly run the qff circuit; wave w measures qubit w
    const float inv = inv_s;
    float2 v[4];
    #pragma unroll
    for (int r = 0; r < 4; ++r){
      float2 m = work[(r<<6) | lane];
      v[r] = make_float2(m.x*inv, m.y*inv);
    }
    sim32(v, lane, (const float2*)qcs);
    float xr, xi, zz;
    measure_one(v, lane, 7 - w, xr, xi, zz);
    if (lane == 0){ exps[w] = 2.f*xr; exps[8+w] = 2.f*xi; exps[16+w] = zz; }
  }
  __syncthreads();
  float a = ff1b[tid];
  const float* wr = ff1_lds + tid*24;
  #pragma unroll
  for (int m2 = 0; m2 < 24; ++m2) a += exps[m2]*wr[m2];
  hT[tid*NB + b] = fmaxf(a, 0.f);   // k-major hT[k][b]
}

// ---------- k_out: 64 vocab rows x 4 K-quarters per block (786 blocks) ----------
__global__ __launch_bounds__(256) void k_out(
    const float* __restrict__ hT, const float* __restrict__ ff2W,
    const float* __restrict__ ff2b, const float* __restrict__ fprobs,
    float* __restrict__ out)
{
  __shared__ float4 smem[2048];   // 32 KB: hT staging, then partial reduction
  const int tid = threadIdx.x;

  if (blockIdx.x == 0 && tid == 0){
    float s = 0.f;
    #pragma unroll
    for (int i = 0; i < 16; ++i) s += fprobs[i];
    out[(size_t)NB*VOCABN] = s * (1.f/16.f);
  }

  { // stage hT -> LDS (coalesced)
    const float4* hT4 = (const float4*)hT;
    #pragma unroll
    for (int i = 0; i < 8; ++i) smem[i*256 + tid] = hT4[i*256 + tid];
  }
  __syncthreads();

  const int r = tid & 63;
  const int q = tid >> 6;          // K-quarter
  const int row = blockIdx.x*64 + r;
  const bool valid = (row < VOCABN);

  float4 a0 = make_float4(0,0,0,0), a1 = a0, a2 = a0, a3 = a0;

  if (valid){
    const float4* wv = (const float4*)(ff2W + (size_t)row * EMBN) + q*32;
    const int kbase = q*128;
    #pragma unroll 8
    for (int c = 0; c < 32; ++c){
      float4 wq = wv[c];
      const int k0 = (kbase + c*4) << 2;
      float4 h00 = smem[k0+0],  h01 = smem[k0+1],  h02 = smem[k0+2],  h03 = smem[k0+3];
      float4 h10 = smem[k0+4],  h11 = smem[k0+5],  h12 = smem[k0+6],  h13 = smem[k0+7];
      float4 h20 = smem[k0+8],  h21 = smem[k0+9],  h22 = smem[k0+10], h23 = smem[k0+11];
      float4 h30 = smem[k0+12], h31 = smem[k0+13], h32 = smem[k0+14], h33 = smem[k0+15];
      a0.x += wq.x*h00.x + wq.y*h10.x + wq.z*h20.x + wq.w*h30.x;
      a0.y += wq.x*h00.y + wq.y*h10.y + wq.z*h20.y + wq.w*h30.y;
      a0.z += wq.x*h00.z + wq.y*h10.z + wq.z*h20.z + wq.w*h30.z;
      a0.w += wq.x*h00.w + wq.y*h10.w + wq.z*h20.w + wq.w*h30.w;
      a1.x += wq.x*h01.x + wq.y*h11.x + wq.z*h21.x + wq.w*h31.x;
      a1.y += wq.x*h01.y + wq.y*h11.y + wq.z*h21.y + wq.w*h31.y;
      a1.z += wq.x*h01.z + wq.y*h11.z + wq.z*h21.z + wq.w*h31.z;
      a1.w += wq.x*h01.w + wq.y*h11.w + wq.z*h21.w + wq.w*h31.w;
      a2.x += wq.x*h02.x + wq.y*h12.x + wq.z*h22.x + wq.w*h32.x;
      a2.y += wq.x*h02.y + wq.y*h12.y + wq.z*h22.y + wq.w*h32.y;
      a2.z += wq.x*h02.z + wq.y*h12.z + wq.z*h22.z + wq.w*h32.z;
      a2.w += wq.x*h02.w + wq.y*h12.w + wq.z*h22.w + wq.w*h32.w;
      a3.x += wq.x*h03.x + wq.y*h13.x + wq.z*h23.x + wq.w*h33.x;
      a3.y += wq.x*h03.y + wq.y*h13.y + wq.z*h23.y + wq.w*h33.y;
      a3.z += wq.x*h03.z + wq.y*h13.z + wq.z*h23.z + wq.w*h33.z;
      a3.w += wq.x*h03.w + wq.y*h13.w + wq.z*h23.w + wq.w*h33.w;
    }
  }
  __syncthreads();

  if (q > 0){   // partials: smem[j*256 + q*64 + r], consecutive lanes -> conflict-free
    smem[0*256 + q*64 + r] = a0;
    smem[1*256 + q*64 + r] = a1;
    smem[2*256 + q*64 + r] = a2;
    smem[3*256 + q*64 + r] = a3;
  }
  __syncthreads();
  if (q == 0 && valid){
    #pragma unroll
    for (int qq = 1; qq < 4; ++qq){
      float4 b0 = smem[0*256 + qq*64 + r], b1 = smem[1*256 + qq*64 + r];
      float4 b2 = smem[2*256 + qq*64 + r], b3 = smem[3*256 + qq*64 + r];
      a0.x += b0.x; a0.y += b0.y; a0.z += b0.z; a0.w += b0.w;
      a1.x += b1.x; a1.y += b1.y; a1.z += b1.z; a1.w += b1.w;
      a2.x += b2.x; a2.y += b2.y; a2.z += b2.z; a2.w += b2.w;
      a3.x += b3.x; a3.y += b3.y; a3.z += b3.z; a3.w += b3.w;
    }
    const float bias = ff2b[row];
    out[(size_t) 0*VOCABN + row] = a0.x + bias;
    out[(size_t) 1*VOCABN + row] = a0.y + bias;
    out[(size_t) 2*VOCABN + row] = a0.z + bias;
    out[(size_t) 3*VOCABN + row] = a0.w + bias;
    out[(size_t) 4*VOCABN + row] = a1.x + bias;
    out[(size_t) 5*VOCABN + row] = a1.y + bias;
    out[(size_t) 6*VOCABN + row] = a1.z + bias;
    out[(size_t) 7*VOCABN + row] = a1.w + bias;
    out[(size_t) 8*VOCABN + row] = a2.x + bias;
    out[(size_t) 9*VOCABN + row] = a2.y + bias;
    out[(size_t)10*VOCABN + row] = a2.z + bias;
    out[(size_t)11*VOCABN + row] = a2.w + bias;
    out[(size_t)12*VOCABN + row] = a3.x + bias;
    out[(size_t)13*VOCABN + row] = a3.y + bias;
    out[(size_t)14*VOCABN + row] = a3.z + bias;
    out[(size_t)15*VOCABN + row] = a3.w + bias;
  }
}

extern "C" void kernel_launch(void* const* d_in, const int* in_sizes, int n_in,
                              void* d_out, int out_size, void* d_ws, size_t ws_size,
                              hipStream_t stream)
{
  const int*   x     = (const int*)  d_in[0];
  const float* embW  = (const float*)d_in[1];
  const float* e2rW  = (const float*)d_in[2];
  const float* e2rb  = (const float*)d_in[3];
  const float* poly  = (const float*)d_in[4];
  const float* mixri = (const float*)d_in[5];
  const float* qff   = (const float*)d_in[6];
  const float* ff1W  = (const float*)d_in[7];
  const float* ff1b  = (const float*)d_in[8];
  const float* ff2W  = (const float*)d_in[9];
  const float* ff2b  = (const float*)d_in[10];
  float* out = (float*)d_out;
  float* ws  = (float*)d_ws;

  float*  wcs    = ws;             // 32768 floats
  float*  coeffs = ws + 32768;     // 32
  float*  qcs    = ws + 32800;     // 64
  float*  hT     = ws + 32864;     // 8192
  float*  fprobs = ws + 41056;     // 16
  float2* accs   = (float2*)(ws + 41072);   // 16*256 float2 = 8192 floats
  float2* S1     = (float2*)(ws + 49264);   // 256*256 float2 = 131072 floats
  float2* S2     = (float2*)(ws + 180336);  // 131072 floats

  k_prep <<<256, 64, 0, stream>>>(x, embW, e2rW, e2rb, mixri, qff, wcs, coeffs, qcs);
  k_deg1 <<<256, 64, 0, stream>>>(wcs, coeffs, S1);
  k_deg  <<<256, 64, 0, stream>>>(S1, S2, wcs, coeffs, poly, accs, 1);
  k_deg  <<<256, 64, 0, stream>>>(S2, S1, wcs, coeffs, poly, accs, 2);
  k_final<<<NB, 512, 0, stream>>>(S1, accs, poly, qcs, ff1W, ff1b, hT, fprobs);
  k_out  <<<(VOCABN + 63)/64, 256, 0, stream>>>(hT, ff2W, ff2b, fprobs, out);
}